// Round 8
// baseline (31316.330 us; speedup 1.0000x reference)
//
#include <hip/hip_runtime.h>
#include <cstdint>
#include <cstddef>

// Problem constants
#define S_  4096
#define L_  16
#define E_  512
#define H_  512
#define G4_ 2048
#define T_  64
#define WORD_WGS 128   // each owns 4 hidden units (16 gate rows)
#define CHAR_WGS 128   // each owns (m-group, hu-tile), 2 m-tiles sequentially
#define ALL_WGS  (WORD_WGS + CHAR_WGS)

__device__ __forceinline__ float sigmoidf_(float x) {
    return 1.0f / (1.0f + __expf(-x));
}
__device__ __forceinline__ float fast_tanhf_(float x) {
    return 1.0f - 2.0f / (__expf(2.0f * x) + 1.0f);
}

// ---------------------------------------------------------------------------
// fp32 GEMM for word gx (proven):  C[m,n] = sum_k A1[idx(m)][k] * B1[n][k]
// ---------------------------------------------------------------------------
#define BM 128
#define BN 128
#define BK 16

__global__ __launch_bounds__(256, 2)
void gemm_nt_kernel(const float* __restrict__ A1, const int* __restrict__ idxA,
                    int idxStride, int idxOff,
                    const float* __restrict__ B1, int K, int N,
                    float* __restrict__ C)
{
    __shared__ float As_[BK][BM + 4];
    __shared__ float Bs_[BK][BN + 4];
    __shared__ int   rIdx_[BM];

    const int tid = threadIdx.x;
    const int m0 = blockIdx.y * BM;
    const int n0 = blockIdx.x * BN;
    if (tid < BM)
        rIdx_[tid] = idxA[(size_t)(m0 + tid) * idxStride + idxOff];

    const int tx = tid & 15;
    const int ty = tid >> 4;
    const int ar = tid >> 2;
    const int aq = tid & 3;

    float acc[8][8];
#pragma unroll
    for (int i = 0; i < 8; ++i)
#pragma unroll
        for (int j = 0; j < 8; ++j) acc[i][j] = 0.f;

    for (int k0 = 0; k0 < K; k0 += BK) {
        __syncthreads();
#pragma unroll
        for (int part = 0; part < 2; ++part) {
            const int row = ar + part * 64;
            const int grA = rIdx_[row];
            float4 av = *(const float4*)(A1 + (size_t)grA * K + k0 + aq * 4);
            float4 bv = *(const float4*)(B1 + (size_t)(n0 + row) * K + k0 + aq * 4);
            As_[aq * 4 + 0][row] = av.x; As_[aq * 4 + 1][row] = av.y;
            As_[aq * 4 + 2][row] = av.z; As_[aq * 4 + 3][row] = av.w;
            Bs_[aq * 4 + 0][row] = bv.x; Bs_[aq * 4 + 1][row] = bv.y;
            Bs_[aq * 4 + 2][row] = bv.z; Bs_[aq * 4 + 3][row] = bv.w;
        }
        __syncthreads();
#pragma unroll
        for (int kk = 0; kk < BK; ++kk) {
            const float4 a0 = *(const float4*)&As_[kk][ty * 4];
            const float4 a1 = *(const float4*)&As_[kk][64 + ty * 4];
            const float4 b0 = *(const float4*)&Bs_[kk][tx * 4];
            const float4 b1 = *(const float4*)&Bs_[kk][64 + tx * 4];
            const float a[8] = {a0.x, a0.y, a0.z, a0.w, a1.x, a1.y, a1.z, a1.w};
            const float b[8] = {b0.x, b0.y, b0.z, b0.w, b1.x, b1.y, b1.z, b1.w};
#pragma unroll
            for (int i = 0; i < 8; ++i)
#pragma unroll
                for (int j = 0; j < 8; ++j)
                    acc[i][j] = fmaf(a[i], b[j], acc[i][j]);
        }
    }
#pragma unroll
    for (int ri = 0; ri < 2; ++ri)
#pragma unroll
        for (int i = 0; i < 4; ++i) {
            const int m = m0 + ri * 64 + ty * 4 + i;
            float4 v0 = make_float4(acc[ri * 4 + i][0], acc[ri * 4 + i][1],
                                    acc[ri * 4 + i][2], acc[ri * 4 + i][3]);
            float4 v1 = make_float4(acc[ri * 4 + i][4], acc[ri * 4 + i][5],
                                    acc[ri * 4 + i][6], acc[ri * 4 + i][7]);
            *(float4*)(C + (size_t)m * N + n0 + tx * 4)      = v0;
            *(float4*)(C + (size_t)m * N + n0 + 64 + tx * 4) = v1;
        }
}

// ---------------------------------------------------------------------------
// Fused: wgs 0..127 word LSTM, wgs 128..255 char LSTM. 256 wgs on 256 CUs.
// Co-residency: VGPR<=128 (launch_bounds 512,4) -> 2 wgs/CU capacity (512
// total) >= 256 grid, 2x margin -> no dispatch deadlock.
//
// Word: wg owns 4 h-units (16 gate rows). Whh slice = 16 f32/thread in VGPRs.
// Per-step: matvec (h from LDS broadcast) -> 32-lane shfl reduce -> wave0
// computes gates, publishes h (4 agent stores), release-stores flag[wg]=t+1
// (wave-level vmcnt drain covers the h stores), then wave0's 64 lanes poll
// all 128 flags (2 each, ACQUIRE). WAR safety: flag[w]=t+1 is program-order
// after wg w's step-(t-1) reads of buf[t&1], so observing all flags>=t+1
// excludes the overwrite at step t+1.
//
// Char: Round-6 tile (128m x 64hu, 4 gates in-register), 2 m-tiles per wg =
// 32 virtual steps; read-barrier / write-barrier pair per vstep excludes the
// h_c WAR race (tiles row-disjoint within a vstep).
// ---------------------------------------------------------------------------
__global__ __launch_bounds__(512, 4)
void fused_lstm_kernel(const float* __restrict__ gxw,
                       const float* __restrict__ Whh_w,
                       const float* __restrict__ bih_w,
                       const float* __restrict__ bhh_w,
                       float* __restrict__ hsw, float* __restrict__ h_buf,
                       unsigned int* __restrict__ cnt,
                       const int* __restrict__ char_in,
                       const int* __restrict__ lengths,
                       const float* __restrict__ char_emb,
                       const float* __restrict__ Wih_c,
                       const float* __restrict__ Whh_c,
                       const float* __restrict__ bih_c,
                       const float* __restrict__ bhh_c,
                       float* __restrict__ h_c, float* __restrict__ c_c,
                       float* __restrict__ osum)
{
    __shared__ __align__(16) unsigned char smem[27392];
    const int tid = threadIdx.x;

    if (blockIdx.x < WORD_WGS) {
        // ------------------------- word LSTM -------------------------
        float* h_lds    = (float*)smem;            // 512 f
        float* gate_lds = (float*)(smem + 2048);   // 16 f
        float* wb       = (float*)(smem + 2112);   // 16 f

        const int wg   = blockIdx.x;
        const int base = wg * 4;              // h-units [base, base+4)
        const int r    = tid >> 5;            // local gate row 0..15
        const int p    = tid & 31;            // 32-way k split
        const int grow = (r >> 2) * 512 + base + (r & 3);

        // step-invariant Whh slice: 4 float4 = 16 VGPRs (no spill pressure)
        float4 w0, w1, w2, w3;
        {
            const float4* Wrow = (const float4*)(Whh_w + (size_t)grow * 512);
            w0 = Wrow[p];       w1 = Wrow[32 + p];
            w2 = Wrow[64 + p];  w3 = Wrow[96 + p];
        }
        if (tid < 16) {
            const int gr = (tid >> 2) * 512 + base + (tid & 3);
            wb[tid] = bih_w[gr] + bhh_w[gr];
        }
        if (tid < 128) ((float4*)h_lds)[tid] = make_float4(0.f, 0.f, 0.f, 0.f);
        float cstate = 0.f;
        __syncthreads();

        unsigned int* flags = cnt + 64;   // flag[w] at cnt[64 + w*16]
        float gxv = (p == 0) ? gxw[grow] : 0.f;

        for (int t = 0; t < S_; ++t) {
            float gxn = 0.f;
            if (p == 0 && t + 1 < S_) gxn = gxw[(size_t)(t + 1) * G4_ + grow];

            const float4* h4 = (const float4*)h_lds;
            float4 ha = h4[p], hb = h4[32 + p], hc = h4[64 + p], hd = h4[96 + p];
            float s = 0.f;
            s = fmaf(w0.x, ha.x, s); s = fmaf(w0.y, ha.y, s);
            s = fmaf(w0.z, ha.z, s); s = fmaf(w0.w, ha.w, s);
            s = fmaf(w1.x, hb.x, s); s = fmaf(w1.y, hb.y, s);
            s = fmaf(w1.z, hb.z, s); s = fmaf(w1.w, hb.w, s);
            s = fmaf(w2.x, hc.x, s); s = fmaf(w2.y, hc.y, s);
            s = fmaf(w2.z, hc.z, s); s = fmaf(w2.w, hc.w, s);
            s = fmaf(w3.x, hd.x, s); s = fmaf(w3.y, hd.y, s);
            s = fmaf(w3.z, hd.z, s); s = fmaf(w3.w, hd.w, s);
            s += __shfl_xor(s, 16);
            s += __shfl_xor(s, 8);
            s += __shfl_xor(s, 4);
            s += __shfl_xor(s, 2);
            s += __shfl_xor(s, 1);
            if (p == 0) gate_lds[r] = s + gxv + wb[r];
            __syncthreads();                        // sync1: gates ready

            if (tid < 64) {                          // wave0 only
                if (tid < 4) {
                    const float gi = gate_lds[tid];
                    const float gf = gate_lds[4 + tid];
                    const float gg = gate_lds[8 + tid];
                    const float go = gate_lds[12 + tid];
                    const float cn = sigmoidf_(gf) * cstate
                                   + sigmoidf_(gi) * fast_tanhf_(gg);
                    cstate = cn;
                    const float hn = sigmoidf_(go) * fast_tanhf_(cn);
                    hsw[(size_t)t * H_ + base + tid] = hn;
                    __hip_atomic_store(&h_buf[((t + 1) & 1) * H_ + base + tid],
                                       hn, __ATOMIC_RELAXED,
                                       __HIP_MEMORY_SCOPE_AGENT);
                }
                // release: wave-level vmcnt drain covers lanes 0..3's stores
                if (tid == 0)
                    __hip_atomic_store(&flags[wg * 16],
                                       (unsigned int)(t + 1), __ATOMIC_RELEASE,
                                       __HIP_MEMORY_SCOPE_AGENT);
                const unsigned int tp1 = (unsigned int)(t + 1);
                for (;;) {
                    unsigned int f1 = __hip_atomic_load(
                        &flags[tid * 16], __ATOMIC_ACQUIRE,
                        __HIP_MEMORY_SCOPE_AGENT);
                    unsigned int f2 = __hip_atomic_load(
                        &flags[(64 + tid) * 16], __ATOMIC_ACQUIRE,
                        __HIP_MEMORY_SCOPE_AGENT);
                    if (__all((int)(f1 >= tp1 && f2 >= tp1))) break;
                    __builtin_amdgcn_s_sleep(1);
                }
            }
            __syncthreads();                        // sync2: flags confirmed
            h_lds[tid] = __hip_atomic_load(&h_buf[((t + 1) & 1) * H_ + tid],
                                           __ATOMIC_RELAXED,
                                           __HIP_MEMORY_SCOPE_AGENT);
            __syncthreads();                        // sync3: h ready
            gxv = gxn;
        }
    } else {
        // ------------------------- char LSTM -------------------------
        float (*As)[132] = (float(*)[132])smem;            //  8448 B
        float (*Bs)[260] = (float(*)[260])(smem + 8448);   // 16640 B
        int*   rIdx = (int*)(smem + 25088);                //   512 B
        int*   lens = (int*)(smem + 25600);                //   512 B
        float* cb   = (float*)(smem + 26112);              //  1024 B

        const int cw   = blockIdx.x - WORD_WGS;  // 0..127
        const int mgrp = cw >> 3;                // 0..15
        const int hu0  = (cw & 7) * 64;
        const int tx   = tid & 31;
        const int ty   = tid >> 5;

        if (tid < 256) {
            const int g = tid >> 6, ul = tid & 63;
            const int br = g * 512 + hu0 + ul;
            cb[tid] = bih_c[br] + bhh_c[br];
        }

        for (int l = 0; l < L_; ++l) {
            for (int mt = 0; mt < 2; ++mt) {
                const int m0 = (mgrp + mt * 16) * 128;
                const unsigned int ph = (unsigned int)((l * 2 + mt) * 2);
                if (tid < 128) {
                    rIdx[tid] = char_in[(size_t)(m0 + tid) * L_ + l];
                    lens[tid] = lengths[m0 + tid];
                }

                float acc[8][8];
#pragma unroll
                for (int i = 0; i < 8; ++i)
#pragma unroll
                    for (int j = 0; j < 8; ++j) acc[i][j] = 0.f;

                for (int kt = 0; kt < 64; ++kt) {
                    const int k0 = kt * 16;
                    __syncthreads();   // first iter also covers rIdx/lens/cb
                    const int row = tid >> 2, q = tid & 3;
                    float4 av;
                    if (k0 < 512) {
                        av = *(const float4*)(char_emb
                             + (size_t)rIdx[row] * E_ + k0 + q * 4);
                    } else {
                        const float* hp = h_c + (size_t)(m0 + row) * H_
                                        + (k0 - 512) + q * 4;
                        av.x = __hip_atomic_load(hp + 0, __ATOMIC_RELAXED, __HIP_MEMORY_SCOPE_AGENT);
                        av.y = __hip_atomic_load(hp + 1, __ATOMIC_RELAXED, __HIP_MEMORY_SCOPE_AGENT);
                        av.z = __hip_atomic_load(hp + 2, __ATOMIC_RELAXED, __HIP_MEMORY_SCOPE_AGENT);
                        av.w = __hip_atomic_load(hp + 3, __ATOMIC_RELAXED, __HIP_MEMORY_SCOPE_AGENT);
                    }
                    As[q * 4 + 0][row] = av.x; As[q * 4 + 1][row] = av.y;
                    As[q * 4 + 2][row] = av.z; As[q * 4 + 3][row] = av.w;
#pragma unroll
                    for (int cc = 0; cc < 2; ++cc) {
                        const int c  = row + cc * 128;
                        const int g  = c >> 6, u = c & 63;
                        const int br = g * 512 + hu0 + u;
                        const float* bp = (k0 < 512)
                            ? (Wih_c + (size_t)br * E_ + k0 + q * 4)
                            : (Whh_c + (size_t)br * H_ + (k0 - 512) + q * 4);
                        const float4 bv = *(const float4*)bp;
                        Bs[q * 4 + 0][c] = bv.x; Bs[q * 4 + 1][c] = bv.y;
                        Bs[q * 4 + 2][c] = bv.z; Bs[q * 4 + 3][c] = bv.w;
                    }
                    __syncthreads();
#pragma unroll
                    for (int kk = 0; kk < 16; ++kk) {
                        const float4 a0 = *(const float4*)&As[kk][ty * 8];
                        const float4 a1 = *(const float4*)&As[kk][ty * 8 + 4];
                        const float a[8] = {a0.x, a0.y, a0.z, a0.w,
                                            a1.x, a1.y, a1.z, a1.w};
                        float b[8];
#pragma unroll
                        for (int g = 0; g < 4; ++g) {
                            const float2 bg = *(const float2*)&Bs[kk][g * 64 + 2 * tx];
                            b[(g << 1)]     = bg.x;
                            b[(g << 1) | 1] = bg.y;
                        }
#pragma unroll
                        for (int i = 0; i < 8; ++i)
#pragma unroll
                            for (int j = 0; j < 8; ++j)
                                acc[i][j] = fmaf(a[i], b[j], acc[i][j]);
                    }
                }

                // barrier: all wgs finished reading h_c for this vstep
                __syncthreads();
                if (tid == 0) {
                    __hip_atomic_fetch_add(&cnt[0], 1u, __ATOMIC_RELEASE,
                                           __HIP_MEMORY_SCOPE_AGENT);
                    while (__hip_atomic_load(&cnt[0], __ATOMIC_ACQUIRE,
                                             __HIP_MEMORY_SCOPE_AGENT)
                           < (unsigned)CHAR_WGS * (ph + 1))
                        __builtin_amdgcn_s_sleep(2);
                }
                __syncthreads();

                // epilogue (skip-store freezes masked rows)
#pragma unroll
                for (int i = 0; i < 8; ++i) {
                    const int mr = ty * 8 + i;
                    const int m  = m0 + mr;
                    if (l < lens[mr]) {
                        const int hl = 2 * tx;
                        float* cp = c_c  + (size_t)m * H_ + hu0 + hl;
                        float* op = osum + (size_t)m * H_ + hu0 + hl;
                        float2 c2 = *(float2*)cp;
                        float2 o2 = *(float2*)op;
#pragma unroll
                        for (int u = 0; u < 2; ++u) {
                            const float I = sigmoidf_(acc[i][0 + u] + cb[      hl + u]);
                            const float F = sigmoidf_(acc[i][2 + u] + cb[ 64 + hl + u]);
                            const float G = fast_tanhf_(acc[i][4 + u] + cb[128 + hl + u]);
                            const float O = sigmoidf_(acc[i][6 + u] + cb[192 + hl + u]);
                            const float cv = u ? c2.y : c2.x;
                            const float cn = F * cv + I * G;
                            const float hn = O * fast_tanhf_(cn);
                            if (u) { c2.y = cn; o2.y += hn; }
                            else   { c2.x = cn; o2.x += hn; }
                            __hip_atomic_store(h_c + (size_t)m * H_ + hu0 + hl + u,
                                               hn, __ATOMIC_RELAXED,
                                               __HIP_MEMORY_SCOPE_AGENT);
                        }
                        *(float2*)cp = c2;
                        *(float2*)op = o2;
                    }
                }

                // barrier: all h_c writes done before next vstep's reads
                __syncthreads();
                if (tid == 0) {
                    __hip_atomic_fetch_add(&cnt[0], 1u, __ATOMIC_RELEASE,
                                           __HIP_MEMORY_SCOPE_AGENT);
                    while (__hip_atomic_load(&cnt[0], __ATOMIC_ACQUIRE,
                                             __HIP_MEMORY_SCOPE_AGENT)
                           < (unsigned)CHAR_WGS * (ph + 2))
                        __builtin_amdgcn_s_sleep(2);
                }
                __syncthreads();
            }
        }
    }
}

// ---------------------------------------------------------------------------
// scores + log_softmax (proven)
// ---------------------------------------------------------------------------
__global__ __launch_bounds__(64)
void scores_kernel(const float* __restrict__ hsw, const float* __restrict__ osum,
                   const float* __restrict__ Ww2t, const float* __restrict__ bw2t,
                   const float* __restrict__ Wc2t, const float* __restrict__ bc2t,
                   float* __restrict__ out)
{
    const int s = blockIdx.x;
    const int t = threadIdx.x;
    __shared__ float4 hrow[128], orow[128];
    hrow[t]      = ((const float4*)(hsw + (size_t)s * H_))[t];
    hrow[t + 64] = ((const float4*)(hsw + (size_t)s * H_))[t + 64];
    orow[t]      = ((const float4*)(osum + (size_t)s * H_))[t];
    orow[t + 64] = ((const float4*)(osum + (size_t)s * H_))[t + 64];
    __syncthreads();

    float acc = bw2t[t] + bc2t[t];
    const float4* w1 = (const float4*)(Ww2t + (size_t)t * H_);
    const float4* w2 = (const float4*)(Wc2t + (size_t)t * H_);
#pragma unroll 8
    for (int k = 0; k < 128; ++k) {
        const float4 a = w1[k], hb = hrow[k];
        acc = fmaf(a.x, hb.x, acc); acc = fmaf(a.y, hb.y, acc);
        acc = fmaf(a.z, hb.z, acc); acc = fmaf(a.w, hb.w, acc);
        const float4 b = w2[k], ob = orow[k];
        acc = fmaf(b.x, ob.x, acc); acc = fmaf(b.y, ob.y, acc);
        acc = fmaf(b.z, ob.z, acc); acc = fmaf(b.w, ob.w, acc);
    }
    float m = acc;
#pragma unroll
    for (int off = 32; off > 0; off >>= 1) m = fmaxf(m, __shfl_xor(m, off));
    float sum = __expf(acc - m);
#pragma unroll
    for (int off = 32; off > 0; off >>= 1) sum += __shfl_xor(sum, off);
    out[(size_t)s * T_ + t] = acc - m - __logf(sum);
}

// ---------------------------------------------------------------------------
extern "C" void kernel_launch(void* const* d_in, const int* in_sizes, int n_in,
                              void* d_out, int out_size, void* d_ws, size_t ws_size,
                              hipStream_t stream)
{
    (void)in_sizes; (void)n_in; (void)out_size; (void)ws_size;

    const int*   sent_in  = (const int*)d_in[0];
    const int*   char_in  = (const int*)d_in[1];
    const int*   lengths  = (const int*)d_in[2];
    const float* word_emb = (const float*)d_in[3];
    const float* char_emb = (const float*)d_in[4];
    const float* Wih_w    = (const float*)d_in[5];
    const float* Whh_w    = (const float*)d_in[6];
    const float* bih_w    = (const float*)d_in[7];
    const float* bhh_w    = (const float*)d_in[8];
    const float* Wih_c    = (const float*)d_in[9];
    const float* Whh_c    = (const float*)d_in[10];
    const float* bih_c    = (const float*)d_in[11];
    const float* bhh_c    = (const float*)d_in[12];
    const float* Ww2t     = (const float*)d_in[13];
    const float* bw2t     = (const float*)d_in[14];
    const float* Wc2t     = (const float*)d_in[15];
    const float* bc2t     = (const float*)d_in[16];

    char* ws = (char*)d_ws;
    float* gxw  = (float*)(ws + 0);          // 33,554,432
    float* hsw  = (float*)(ws + 33554432);   //  8,388,608
    float* h_c  = (float*)(ws + 41943040);   //  8,388,608
    float* c_c  = (float*)(ws + 50331648);   //  8,388,608
    float* osum = (float*)(ws + 58720256);   //  8,388,608
    float* hbuf = (float*)(ws + 67108864);   //      4,096
    unsigned int* cnt = (unsigned int*)(ws + 67112960); // 16,384
    // cnt[0] = char barrier counter; word flags at cnt[64 + wg*16]

    hipMemsetAsync(hbuf, 0, 4096, stream);
    hipMemsetAsync(cnt,  0, 16384, stream);
    hipMemsetAsync(h_c,  0, 8388608, stream);
    hipMemsetAsync(c_c,  0, 8388608, stream);
    hipMemsetAsync(osum, 0, 8388608, stream);

    const dim3 gemmGrid(G4_ / BN, S_ / BM);
    gemm_nt_kernel<<<gemmGrid, 256, 0, stream>>>(
        word_emb, sent_in, /*idxStride=*/1, /*idxOff=*/0,
        Wih_w, /*K=*/E_, G4_, gxw);

    fused_lstm_kernel<<<ALL_WGS, 512, 0, stream>>>(
        gxw, Whh_w, bih_w, bhh_w, hsw, hbuf, cnt,
        char_in, lengths, char_emb, Wih_c, Whh_c, bih_c, bhh_c,
        h_c, c_c, osum);

    scores_kernel<<<S_, 64, 0, stream>>>(hsw, osum, Ww2t, bw2t, Wc2t, bc2t,
                                         (float*)d_out);
}

// Round 12
// 25962.735 us; speedup vs baseline: 1.2062x; 1.2062x over previous
//
#include <hip/hip_runtime.h>
#include <cstdint>
#include <cstddef>

// Problem constants
#define S_  4096
#define L_  16
#define E_  512
#define H_  512
#define G4_ 2048
#define T_  64
#define WORD_WGS 128   // each owns 4 hidden units (16 gate rows)
#define CHAR_WGS 128   // each owns (m-group, hu-tile), 2 m-tiles sequentially
#define ALL_WGS  (WORD_WGS + CHAR_WGS)

__device__ __forceinline__ float sigmoidf_(float x) {
    return 1.0f / (1.0f + __expf(-x));
}
__device__ __forceinline__ float fast_tanhf_(float x) {
    return 1.0f - 2.0f / (__expf(2.0f * x) + 1.0f);
}

// ---------------------------------------------------------------------------
// fp32 GEMM for word gx (proven):  C[m,n] = sum_k A1[idx(m)][k] * B1[n][k]
// ---------------------------------------------------------------------------
#define BM 128
#define BN 128
#define BK 16

__global__ __launch_bounds__(256, 2)
void gemm_nt_kernel(const float* __restrict__ A1, const int* __restrict__ idxA,
                    int idxStride, int idxOff,
                    const float* __restrict__ B1, int K, int N,
                    float* __restrict__ C)
{
    __shared__ float As_[BK][BM + 4];
    __shared__ float Bs_[BK][BN + 4];
    __shared__ int   rIdx_[BM];

    const int tid = threadIdx.x;
    const int m0 = blockIdx.y * BM;
    const int n0 = blockIdx.x * BN;
    if (tid < BM)
        rIdx_[tid] = idxA[(size_t)(m0 + tid) * idxStride + idxOff];

    const int tx = tid & 15;
    const int ty = tid >> 4;
    const int ar = tid >> 2;
    const int aq = tid & 3;

    float acc[8][8];
#pragma unroll
    for (int i = 0; i < 8; ++i)
#pragma unroll
        for (int j = 0; j < 8; ++j) acc[i][j] = 0.f;

    for (int k0 = 0; k0 < K; k0 += BK) {
        __syncthreads();
#pragma unroll
        for (int part = 0; part < 2; ++part) {
            const int row = ar + part * 64;
            const int grA = rIdx_[row];
            float4 av = *(const float4*)(A1 + (size_t)grA * K + k0 + aq * 4);
            float4 bv = *(const float4*)(B1 + (size_t)(n0 + row) * K + k0 + aq * 4);
            As_[aq * 4 + 0][row] = av.x; As_[aq * 4 + 1][row] = av.y;
            As_[aq * 4 + 2][row] = av.z; As_[aq * 4 + 3][row] = av.w;
            Bs_[aq * 4 + 0][row] = bv.x; Bs_[aq * 4 + 1][row] = bv.y;
            Bs_[aq * 4 + 2][row] = bv.z; Bs_[aq * 4 + 3][row] = bv.w;
        }
        __syncthreads();
#pragma unroll
        for (int kk = 0; kk < BK; ++kk) {
            const float4 a0 = *(const float4*)&As_[kk][ty * 4];
            const float4 a1 = *(const float4*)&As_[kk][64 + ty * 4];
            const float4 b0 = *(const float4*)&Bs_[kk][tx * 4];
            const float4 b1 = *(const float4*)&Bs_[kk][64 + tx * 4];
            const float a[8] = {a0.x, a0.y, a0.z, a0.w, a1.x, a1.y, a1.z, a1.w};
            const float b[8] = {b0.x, b0.y, b0.z, b0.w, b1.x, b1.y, b1.z, b1.w};
#pragma unroll
            for (int i = 0; i < 8; ++i)
#pragma unroll
                for (int j = 0; j < 8; ++j)
                    acc[i][j] = fmaf(a[i], b[j], acc[i][j]);
        }
    }
#pragma unroll
    for (int ri = 0; ri < 2; ++ri)
#pragma unroll
        for (int i = 0; i < 4; ++i) {
            const int m = m0 + ri * 64 + ty * 4 + i;
            float4 v0 = make_float4(acc[ri * 4 + i][0], acc[ri * 4 + i][1],
                                    acc[ri * 4 + i][2], acc[ri * 4 + i][3]);
            float4 v1 = make_float4(acc[ri * 4 + i][4], acc[ri * 4 + i][5],
                                    acc[ri * 4 + i][6], acc[ri * 4 + i][7]);
            *(float4*)(C + (size_t)m * N + n0 + tx * 4)      = v0;
            *(float4*)(C + (size_t)m * N + n0 + 64 + tx * 4) = v1;
        }
}

// ---------------------------------------------------------------------------
// Fused kernel, 256 wgs. Role by XCD heuristic (wg->XCD = blockIdx%8, perf
// bet only — correctness never depends on placement): (bid&7)<4 -> word
// (XCDs 0-3), else char (XCDs 4-7). Word's L2 writeback/invalidate ops then
// never touch char's L2-resident tiles (R8's 10x WRITE amplification).
//
// Sync design (both-coherence-model-safe, minimal maintenance):
//  - flags are relaxed-polled; progress guaranteed by ACQUIRE poll every 16th
//    iteration (no per-iteration buffer_inv storm).
//  - producer: h stores (relaxed agent) -> s_waitcnt vmcnt(0) -> flag
//    fetch_add RELEASE (RMW executes at device coherence point).
//  - consumer: one ACQUIRE fence after spin exit (single inv/step), then
//    relaxed agent h loads.
// WAR safety on h_buf double-buffer: flag>=t+2 implies all step-t reads
// completed (barrier + vmcnt drain precede the step-t+1 RMW).
// ---------------------------------------------------------------------------
__global__ __launch_bounds__(512, 4)
void fused_lstm_kernel(const float* __restrict__ gxw,
                       const float* __restrict__ Whh_w,
                       const float* __restrict__ bih_w,
                       const float* __restrict__ bhh_w,
                       float* __restrict__ hsw, float* __restrict__ h_buf,
                       unsigned int* __restrict__ cnt,
                       const int* __restrict__ char_in,
                       const int* __restrict__ lengths,
                       const float* __restrict__ char_emb,
                       const float* __restrict__ Wih_c,
                       const float* __restrict__ Whh_c,
                       const float* __restrict__ bih_c,
                       const float* __restrict__ bhh_c,
                       float* __restrict__ h_c, float* __restrict__ c_c,
                       float* __restrict__ osum)
{
    __shared__ __align__(16) unsigned char smem[27648];
    const int tid = threadIdx.x;
    const int bid = blockIdx.x;
    const int role_id = ((bid >> 3) << 2) | (bid & 3);   // 0..127 in each role

    if ((bid & 7) < 4) {
        // ------------------------- word LSTM (XCDs 0-3) -------------------
        float* h_lds    = (float*)smem;            // 512 f
        float* gate_lds = (float*)(smem + 2048);   // 16 f
        float* wb       = (float*)(smem + 2112);   // 16 f

        const int wg   = role_id;             // 0..127
        const int base = wg * 4;              // h-units [base, base+4)
        const int r    = tid >> 5;            // local gate row 0..15
        const int p    = tid & 31;            // 32-way k split
        const int grow = (r >> 2) * 512 + base + (r & 3);

        // step-invariant Whh slice: 4 float4 = 16 VGPRs
        float4 w0, w1, w2, w3;
        {
            const float4* Wrow = (const float4*)(Whh_w + (size_t)grow * 512);
            w0 = Wrow[p];       w1 = Wrow[32 + p];
            w2 = Wrow[64 + p];  w3 = Wrow[96 + p];
        }
        if (tid < 16) {
            const int gr = (tid >> 2) * 512 + base + (tid & 3);
            wb[tid] = bih_w[gr] + bhh_w[gr];
        }
        if (tid < 128) ((float4*)h_lds)[tid] = make_float4(0.f, 0.f, 0.f, 0.f);
        float cstate = 0.f;
        __syncthreads();

        unsigned int* flags = cnt + 64;   // flag[w] at cnt[64 + w*16]
        float gxv = (p == 0) ? gxw[grow] : 0.f;

        for (int t = 0; t < S_; ++t) {
            float gxn = 0.f;
            if (p == 0 && t + 1 < S_) gxn = gxw[(size_t)(t + 1) * G4_ + grow];

            const float4* h4 = (const float4*)h_lds;
            float4 ha = h4[p], hb = h4[32 + p], hc = h4[64 + p], hd = h4[96 + p];
            float s = 0.f;
            s = fmaf(w0.x, ha.x, s); s = fmaf(w0.y, ha.y, s);
            s = fmaf(w0.z, ha.z, s); s = fmaf(w0.w, ha.w, s);
            s = fmaf(w1.x, hb.x, s); s = fmaf(w1.y, hb.y, s);
            s = fmaf(w1.z, hb.z, s); s = fmaf(w1.w, hb.w, s);
            s = fmaf(w2.x, hc.x, s); s = fmaf(w2.y, hc.y, s);
            s = fmaf(w2.z, hc.z, s); s = fmaf(w2.w, hc.w, s);
            s = fmaf(w3.x, hd.x, s); s = fmaf(w3.y, hd.y, s);
            s = fmaf(w3.z, hd.z, s); s = fmaf(w3.w, hd.w, s);
            s += __shfl_xor(s, 16);
            s += __shfl_xor(s, 8);
            s += __shfl_xor(s, 4);
            s += __shfl_xor(s, 2);
            s += __shfl_xor(s, 1);
            if (p == 0) gate_lds[r] = s + gxv + wb[r];
            __syncthreads();                        // sync1: gates ready

            if (tid < 64) {                          // wave0 only
                if (tid < 4) {
                    const float gi = gate_lds[tid];
                    const float gf = gate_lds[4 + tid];
                    const float gg = gate_lds[8 + tid];
                    const float go = gate_lds[12 + tid];
                    const float cn = sigmoidf_(gf) * cstate
                                   + sigmoidf_(gi) * fast_tanhf_(gg);
                    cstate = cn;
                    const float hn = sigmoidf_(go) * fast_tanhf_(cn);
                    hsw[(size_t)t * H_ + base + tid] = hn;
                    __hip_atomic_store(&h_buf[((t + 1) & 1) * H_ + base + tid],
                                       hn, __ATOMIC_RELAXED,
                                       __HIP_MEMORY_SCOPE_AGENT);
                }
                // drain this wave's h stores before publishing the flag
                asm volatile("s_waitcnt vmcnt(0)" ::: "memory");
                if (tid == 0)
                    __hip_atomic_fetch_add(&flags[wg * 16], 1u,
                                           __ATOMIC_RELEASE,
                                           __HIP_MEMORY_SCOPE_AGENT);
                const unsigned int tp1 = (unsigned int)(t + 1);
                int it = 0;
                for (;;) {
                    unsigned int f1, f2;
                    if ((it & 15) == 15) {   // periodic acquire: progress
                        f1 = __hip_atomic_load(&flags[tid * 16],
                                               __ATOMIC_ACQUIRE,
                                               __HIP_MEMORY_SCOPE_AGENT);
                        f2 = __hip_atomic_load(&flags[(64 + tid) * 16],
                                               __ATOMIC_ACQUIRE,
                                               __HIP_MEMORY_SCOPE_AGENT);
                    } else {
                        f1 = __hip_atomic_load(&flags[tid * 16],
                                               __ATOMIC_RELAXED,
                                               __HIP_MEMORY_SCOPE_AGENT);
                        f2 = __hip_atomic_load(&flags[(64 + tid) * 16],
                                               __ATOMIC_RELAXED,
                                               __HIP_MEMORY_SCOPE_AGENT);
                    }
                    if (__all((int)(f1 >= tp1 && f2 >= tp1))) break;
                    __builtin_amdgcn_s_sleep(1);
                    ++it;
                }
                // one acquire per step: make remote h stores readable
                __builtin_amdgcn_fence(__ATOMIC_ACQUIRE, "agent");
            }
            __syncthreads();                        // sync2: flags confirmed
            h_lds[tid] = __hip_atomic_load(&h_buf[((t + 1) & 1) * H_ + tid],
                                           __ATOMIC_RELAXED,
                                           __HIP_MEMORY_SCOPE_AGENT);
            __syncthreads();                        // sync3: h ready
            gxv = gxn;
        }
    } else {
        // ------------------------- char LSTM (XCDs 4-7) --------------------
        float (*As)[132] = (float(*)[132])smem;            //  8448 B
        float (*Bs)[260] = (float(*)[260])(smem + 8448);   // 16640 B
        int*   rIdx = (int*)(smem + 25088);                //   512 B
        int*   lens = (int*)(smem + 25600);                //   512 B
        float* cb   = (float*)(smem + 26112);              //  1024 B

        const int cw   = role_id;                // 0..127
        const int mgrp = cw >> 3;                // 0..15
        const int hu0  = (cw & 7) * 64;
        const int tx   = tid & 31;
        const int ty   = tid >> 5;

        if (tid < 256) {
            const int g = tid >> 6, ul = tid & 63;
            const int br = g * 512 + hu0 + ul;
            cb[tid] = bih_c[br] + bhh_c[br];
        }

        for (int l = 0; l < L_; ++l) {
            for (int mt = 0; mt < 2; ++mt) {
                const int m0 = (mgrp + mt * 16) * 128;
                const unsigned int ph = (unsigned int)((l * 2 + mt) * 2);
                if (tid < 128) {
                    rIdx[tid] = char_in[(size_t)(m0 + tid) * L_ + l];
                    lens[tid] = lengths[m0 + tid];
                }

                float acc[8][8];
#pragma unroll
                for (int i = 0; i < 8; ++i)
#pragma unroll
                    for (int j = 0; j < 8; ++j) acc[i][j] = 0.f;

                for (int kt = 0; kt < 64; ++kt) {
                    const int k0 = kt * 16;
                    __syncthreads();   // first iter also covers rIdx/lens/cb
                    const int row = tid >> 2, q = tid & 3;
                    float4 av;
                    if (k0 < 512) {
                        av = *(const float4*)(char_emb
                             + (size_t)rIdx[row] * E_ + k0 + q * 4);
                    } else {
                        const float* hp = h_c + (size_t)(m0 + row) * H_
                                        + (k0 - 512) + q * 4;
                        av.x = __hip_atomic_load(hp + 0, __ATOMIC_RELAXED, __HIP_MEMORY_SCOPE_AGENT);
                        av.y = __hip_atomic_load(hp + 1, __ATOMIC_RELAXED, __HIP_MEMORY_SCOPE_AGENT);
                        av.z = __hip_atomic_load(hp + 2, __ATOMIC_RELAXED, __HIP_MEMORY_SCOPE_AGENT);
                        av.w = __hip_atomic_load(hp + 3, __ATOMIC_RELAXED, __HIP_MEMORY_SCOPE_AGENT);
                    }
                    As[q * 4 + 0][row] = av.x; As[q * 4 + 1][row] = av.y;
                    As[q * 4 + 2][row] = av.z; As[q * 4 + 3][row] = av.w;
#pragma unroll
                    for (int cc = 0; cc < 2; ++cc) {
                        const int c  = row + cc * 128;
                        const int g  = c >> 6, u = c & 63;
                        const int br = g * 512 + hu0 + u;
                        const float* bp = (k0 < 512)
                            ? (Wih_c + (size_t)br * E_ + k0 + q * 4)
                            : (Whh_c + (size_t)br * H_ + (k0 - 512) + q * 4);
                        const float4 bv = *(const float4*)bp;
                        Bs[q * 4 + 0][c] = bv.x; Bs[q * 4 + 1][c] = bv.y;
                        Bs[q * 4 + 2][c] = bv.z; Bs[q * 4 + 3][c] = bv.w;
                    }
                    __syncthreads();
#pragma unroll
                    for (int kk = 0; kk < 16; ++kk) {
                        const float4 a0 = *(const float4*)&As[kk][ty * 8];
                        const float4 a1 = *(const float4*)&As[kk][ty * 8 + 4];
                        const float a[8] = {a0.x, a0.y, a0.z, a0.w,
                                            a1.x, a1.y, a1.z, a1.w};
                        float b[8];
#pragma unroll
                        for (int g = 0; g < 4; ++g) {
                            const float2 bg = *(const float2*)&Bs[kk][g * 64 + 2 * tx];
                            b[(g << 1)]     = bg.x;
                            b[(g << 1) | 1] = bg.y;
                        }
#pragma unroll
                        for (int i = 0; i < 8; ++i)
#pragma unroll
                            for (int j = 0; j < 8; ++j)
                                acc[i][j] = fmaf(a[i], b[j], acc[i][j]);
                    }
                }

                // barrier: all wgs finished reading h_c for this vstep
                __syncthreads();
                if (tid == 0) {
                    __hip_atomic_fetch_add(&cnt[0], 1u, __ATOMIC_RELEASE,
                                           __HIP_MEMORY_SCOPE_AGENT);
                    while (__hip_atomic_load(&cnt[0], __ATOMIC_ACQUIRE,
                                             __HIP_MEMORY_SCOPE_AGENT)
                           < (unsigned)CHAR_WGS * (ph + 1))
                        __builtin_amdgcn_s_sleep(2);
                }
                __syncthreads();

                // epilogue (skip-store freezes masked rows)
#pragma unroll
                for (int i = 0; i < 8; ++i) {
                    const int mr = ty * 8 + i;
                    const int m  = m0 + mr;
                    if (l < lens[mr]) {
                        const int hl = 2 * tx;
                        float* cp = c_c  + (size_t)m * H_ + hu0 + hl;
                        float* op = osum + (size_t)m * H_ + hu0 + hl;
                        float2 c2 = *(float2*)cp;
                        float2 o2 = *(float2*)op;
#pragma unroll
                        for (int u = 0; u < 2; ++u) {
                            const float I = sigmoidf_(acc[i][0 + u] + cb[      hl + u]);
                            const float F = sigmoidf_(acc[i][2 + u] + cb[ 64 + hl + u]);
                            const float G = fast_tanhf_(acc[i][4 + u] + cb[128 + hl + u]);
                            const float O = sigmoidf_(acc[i][6 + u] + cb[192 + hl + u]);
                            const float cv = u ? c2.y : c2.x;
                            const float cn = F * cv + I * G;
                            const float hn = O * fast_tanhf_(cn);
                            if (u) { c2.y = cn; o2.y += hn; }
                            else   { c2.x = cn; o2.x += hn; }
                            __hip_atomic_store(h_c + (size_t)m * H_ + hu0 + hl + u,
                                               hn, __ATOMIC_RELAXED,
                                               __HIP_MEMORY_SCOPE_AGENT);
                        }
                        *(float2*)cp = c2;
                        *(float2*)op = o2;
                    }
                }

                // barrier: all h_c writes done before next vstep's reads
                __syncthreads();
                if (tid == 0) {
                    __hip_atomic_fetch_add(&cnt[0], 1u, __ATOMIC_RELEASE,
                                           __HIP_MEMORY_SCOPE_AGENT);
                    while (__hip_atomic_load(&cnt[0], __ATOMIC_ACQUIRE,
                                             __HIP_MEMORY_SCOPE_AGENT)
                           < (unsigned)CHAR_WGS * (ph + 2))
                        __builtin_amdgcn_s_sleep(2);
                }
                __syncthreads();
            }
        }
    }
}

// ---------------------------------------------------------------------------
// scores + log_softmax (proven)
// ---------------------------------------------------------------------------
__global__ __launch_bounds__(64)
void scores_kernel(const float* __restrict__ hsw, const float* __restrict__ osum,
                   const float* __restrict__ Ww2t, const float* __restrict__ bw2t,
                   const float* __restrict__ Wc2t, const float* __restrict__ bc2t,
                   float* __restrict__ out)
{
    const int s = blockIdx.x;
    const int t = threadIdx.x;
    __shared__ float4 hrow[128], orow[128];
    hrow[t]      = ((const float4*)(hsw + (size_t)s * H_))[t];
    hrow[t + 64] = ((const float4*)(hsw + (size_t)s * H_))[t + 64];
    orow[t]      = ((const float4*)(osum + (size_t)s * H_))[t];
    orow[t + 64] = ((const float4*)(osum + (size_t)s * H_))[t + 64];
    __syncthreads();

    float acc = bw2t[t] + bc2t[t];
    const float4* w1 = (const float4*)(Ww2t + (size_t)t * H_);
    const float4* w2 = (const float4*)(Wc2t + (size_t)t * H_);
#pragma unroll 8
    for (int k = 0; k < 128; ++k) {
        const float4 a = w1[k], hb = hrow[k];
        acc = fmaf(a.x, hb.x, acc); acc = fmaf(a.y, hb.y, acc);
        acc = fmaf(a.z, hb.z, acc); acc = fmaf(a.w, hb.w, acc);
        const float4 b = w2[k], ob = orow[k];
        acc = fmaf(b.x, ob.x, acc); acc = fmaf(b.y, ob.y, acc);
        acc = fmaf(b.z, ob.z, acc); acc = fmaf(b.w, ob.w, acc);
    }
    float m = acc;
#pragma unroll
    for (int off = 32; off > 0; off >>= 1) m = fmaxf(m, __shfl_xor(m, off));
    float sum = __expf(acc - m);
#pragma unroll
    for (int off = 32; off > 0; off >>= 1) sum += __shfl_xor(sum, off);
    out[(size_t)s * T_ + t] = acc - m - __logf(sum);
}

// ---------------------------------------------------------------------------
extern "C" void kernel_launch(void* const* d_in, const int* in_sizes, int n_in,
                              void* d_out, int out_size, void* d_ws, size_t ws_size,
                              hipStream_t stream)
{
    (void)in_sizes; (void)n_in; (void)out_size; (void)ws_size;

    const int*   sent_in  = (const int*)d_in[0];
    const int*   char_in  = (const int*)d_in[1];
    const int*   lengths  = (const int*)d_in[2];
    const float* word_emb = (const float*)d_in[3];
    const float* char_emb = (const float*)d_in[4];
    const float* Wih_w    = (const float*)d_in[5];
    const float* Whh_w    = (const float*)d_in[6];
    const float* bih_w    = (const float*)d_in[7];
    const float* bhh_w    = (const float*)d_in[8];
    const float* Wih_c    = (const float*)d_in[9];
    const float* Whh_c    = (const float*)d_in[10];
    const float* bih_c    = (const float*)d_in[11];
    const float* bhh_c    = (const float*)d_in[12];
    const float* Ww2t     = (const float*)d_in[13];
    const float* bw2t     = (const float*)d_in[14];
    const float* Wc2t     = (const float*)d_in[15];
    const float* bc2t     = (const float*)d_in[16];

    char* ws = (char*)d_ws;
    float* gxw  = (float*)(ws + 0);          // 33,554,432
    float* hsw  = (float*)(ws + 33554432);   //  8,388,608
    float* h_c  = (float*)(ws + 41943040);   //  8,388,608
    float* c_c  = (float*)(ws + 50331648);   //  8,388,608
    float* osum = (float*)(ws + 58720256);   //  8,388,608
    float* hbuf = (float*)(ws + 67108864);   //      4,096
    unsigned int* cnt = (unsigned int*)(ws + 67112960); // 16,384
    // cnt[0] = char barrier counter; word flags at cnt[64 + wg*16]

    hipMemsetAsync(hbuf, 0, 4096, stream);
    hipMemsetAsync(cnt,  0, 16384, stream);
    hipMemsetAsync(h_c,  0, 8388608, stream);
    hipMemsetAsync(c_c,  0, 8388608, stream);
    hipMemsetAsync(osum, 0, 8388608, stream);

    const dim3 gemmGrid(G4_ / BN, S_ / BM);
    gemm_nt_kernel<<<gemmGrid, 256, 0, stream>>>(
        word_emb, sent_in, /*idxStride=*/1, /*idxOff=*/0,
        Wih_w, /*K=*/E_, G4_, gxw);

    fused_lstm_kernel<<<ALL_WGS, 512, 0, stream>>>(
        gxw, Whh_w, bih_w, bhh_w, hsw, hbuf, cnt,
        char_in, lengths, char_emb, Wih_c, Whh_c, bih_c, bhh_c,
        h_c, c_c, osum);

    scores_kernel<<<S_, 64, 0, stream>>>(hsw, osum, Ww2t, bw2t, Wc2t, bc2t,
                                         (float*)d_out);
}